// Round 8
// baseline (207.932 us; speedup 1.0000x reference)
//
#include <hip/hip_runtime.h>
#include <cstddef>
#include <cstdint>

#define Mq   2048      // B*P
#define Lq   30
#define N1q  1024      // FH
#define N2q  512       // FH/2
#define K1q  1536      // 2*H
#define Hq   768
#define NBLK 512       // loss blocks

// Entire head is LINEAR (LeakyReLU slope 1.0 == identity):
//   logits = feat @ W123 + btot,  W123 = W1@W2@W3 (1536x30 f32),
//   btot = b1@W2@W3 + b2@W3 + b3.
// R7 lesson: the tiny collapse kernels were LATENCY-bound (<1 block/CU, unroll-4,
// cold caches). R8: deeper unroll (16 in flight), j-split prep1 (2x TLP),
// W1 cache-warm blocks, and a loss dot that reads W123 once per block (4x less).

// 16-wide dot body: 4 float4 row loads + 16 LDS reads + 16 FMAs in flight.
// Accumulator<-j mapping identical to the old unroll-4 (s0 gets j%4==0 etc).
#define G16(P, OFS) do {                                                      \
  const float4 a0_ = *(const float4*)((P) + (OFS));                           \
  const float4 a1_ = *(const float4*)((P) + (OFS) + 4);                       \
  const float4 a2_ = *(const float4*)((P) + (OFS) + 8);                       \
  const float4 a3_ = *(const float4*)((P) + (OFS) + 12);                      \
  s0 = fmaf(a0_.x, Ws[((OFS) +  0) * Lq + c], s0);                            \
  s1 = fmaf(a0_.y, Ws[((OFS) +  1) * Lq + c], s1);                            \
  s2 = fmaf(a0_.z, Ws[((OFS) +  2) * Lq + c], s2);                            \
  s3 = fmaf(a0_.w, Ws[((OFS) +  3) * Lq + c], s3);                            \
  s0 = fmaf(a1_.x, Ws[((OFS) +  4) * Lq + c], s0);                            \
  s1 = fmaf(a1_.y, Ws[((OFS) +  5) * Lq + c], s1);                            \
  s2 = fmaf(a1_.z, Ws[((OFS) +  6) * Lq + c], s2);                            \
  s3 = fmaf(a1_.w, Ws[((OFS) +  7) * Lq + c], s3);                            \
  s0 = fmaf(a2_.x, Ws[((OFS) +  8) * Lq + c], s0);                            \
  s1 = fmaf(a2_.y, Ws[((OFS) +  9) * Lq + c], s1);                            \
  s2 = fmaf(a2_.z, Ws[((OFS) + 10) * Lq + c], s2);                            \
  s3 = fmaf(a2_.w, Ws[((OFS) + 11) * Lq + c], s3);                            \
  s0 = fmaf(a3_.x, Ws[((OFS) + 12) * Lq + c], s0);                            \
  s1 = fmaf(a3_.y, Ws[((OFS) + 13) * Lq + c], s1);                            \
  s2 = fmaf(a3_.z, Ws[((OFS) + 14) * Lq + c], s2);                            \
  s3 = fmaf(a3_.w, Ws[((OFS) + 15) * Lq + c], s3);                            \
} while (0)

// ---------- prep1: W23 partials (j-split x2) + beff23 + W1 cache-warm
// [0,240):  W23p[s][k][c] = sum_{j in s-half} W2[k][j]*W3[j][c]  (s = bid/120)
// [240]:    beff23 = b2@W3 + b3
// [241,289): stream W1 into L2/L3 (warm for prep2)
__global__ __launch_bounds__(256)
void prep1(const float* __restrict__ W2, const float* __restrict__ W3,
           const float* __restrict__ b2, const float* __restrict__ b3,
           const float* __restrict__ W1, float* __restrict__ W23p,
           float* __restrict__ beff23) {
  const int bid = blockIdx.x, tid = threadIdx.x;
  if (bid < 240) {
    __shared__ float Ws[7680];              // 256 j x 30 c (30 KB)
    const int s   = bid / 120;              // j-half
    const int idx = (bid % 120) * 256 + tid;
    const int k = idx / Lq, c = idx - k * Lq;
    for (int i = tid * 4; i < 7680; i += 1024)
      *(float4*)&Ws[i] = *(const float4*)&W3[s * 7680 + i];
    __syncthreads();
    const float* w2h = W2 + (size_t)k * N2q + s * 256;
    float s0 = 0.f, s1 = 0.f, s2 = 0.f, s3 = 0.f;
    #pragma unroll 4
    for (int j = 0; j < 256; j += 16) G16(w2h, j);
    W23p[(size_t)s * 30720 + idx] = (s0 + s1) + (s2 + s3);
  } else if (bid == 240) {
    __shared__ float R[8][32];
    const int c = tid % Lq, jc = tid / Lq;
    if (tid < 240) {
      float s = 0.f;
      for (int j = jc * 64; j < jc * 64 + 64; ++j)
        s = fmaf(b2[j], W3[(size_t)j * Lq + c], s);
      R[jc][c] = s;
    }
    __syncthreads();
    if (tid < Lq) {
      float t = b3[tid];
      #pragma unroll
      for (int g = 0; g < 8; ++g) t += R[g][tid];
      beff23[tid] = t;
    }
  } else {
    // warm 128 KB of W1 per block (48 blocks cover all 6 MB)
    const float* src = W1 + (size_t)(bid - 241) * 32768;
    float4 acc = {0.f, 0.f, 0.f, 0.f};
    for (int i = tid * 4; i < 32768; i += 1024) {
      const float4 v = *(const float4*)(src + i);
      acc.x += v.x; acc.y += v.y; acc.z += v.z; acc.w += v.w;
    }
    asm volatile("" :: "v"(acc.x), "v"(acc.y), "v"(acc.z), "v"(acc.w));
  }
}

// ---------- prep2: W123 = W1 @ (p0+p1), partials summed during LDS staging; + btot
__global__ __launch_bounds__(256)
void prep2(const float* __restrict__ W1, const float* __restrict__ b1,
           const float* __restrict__ W23p, const float* __restrict__ beff23,
           float* __restrict__ W123, float* __restrict__ btot) {
  const int bid = blockIdx.x, tid = threadIdx.x;
  if (bid < 180) {                          // 180*256 = 46080 = 1536*30 outputs
    __shared__ float Ws[7680];
    const int idx = bid * 256 + tid;
    const int k = idx / Lq, c = idx - k * Lq;
    const float* w1r = W1 + (size_t)k * N1q;
    float s0 = 0.f, s1 = 0.f, s2 = 0.f, s3 = 0.f;
    for (int ph = 0; ph < 4; ++ph) {
      __syncthreads();
      for (int i = tid * 4; i < 7680; i += 1024) {
        const float4 p0 = *(const float4*)&W23p[ph * 7680 + i];
        const float4 p1 = *(const float4*)&W23p[30720 + ph * 7680 + i];
        float4 sm;
        sm.x = p0.x + p1.x; sm.y = p0.y + p1.y;
        sm.z = p0.z + p1.z; sm.w = p0.w + p1.w;
        *(float4*)&Ws[i] = sm;
      }
      __syncthreads();
      const float* w1h = w1r + ph * 256;
      #pragma unroll 4
      for (int j = 0; j < 256; j += 16) G16(w1h, j);
    }
    W123[idx] = (s0 + s1) + (s2 + s3);      // k-major [1536][30]
  } else {
    __shared__ float R[8][32];
    const int c = tid % Lq, jc = tid / Lq;
    if (tid < 240) {
      float s = 0.f;
      for (int j = jc * 128; j < jc * 128 + 128; ++j)
        s = fmaf(b1[j],
                 W23p[(size_t)j * Lq + c] + W23p[30720 + (size_t)j * Lq + c], s);
      R[jc][c] = s;
    }
    __syncthreads();
    if (tid < Lq) {
      float t = beff23[tid];
      #pragma unroll
      for (int g = 0; g < 8; ++g) t += R[g][tid];
      btot[tid] = t;
    }
  }
}

// ---------- loss: gather 4 feat rows -> K-split dot (wave w owns k-range,
// accumulates ALL 4 rows per weight load -> 4x less W123 traffic) -> loss
__global__ __launch_bounds__(256)
void loss_kernel(const float* __restrict__ tok, const float* __restrict__ pool,
                 const int* __restrict__ npos, const float* __restrict__ W123,
                 const float* __restrict__ btot, const float* __restrict__ labels,
                 float* __restrict__ part) {
  __shared__ float hrow[4][1536];
  __shared__ float red2[4][4][32];   // [wave][row][c]
  __shared__ float red[4][5];
  const int tid = threadIdx.x, w = tid >> 6, lane = tid & 63;
  const int mbase = blockIdx.x * 4;

  {  // gather: wave w loads feat row w (tok[pos] ++ pool)
    const int m = mbase + w;
    const int bI = m >> 5, p = m & 31;
    const int pos = npos[bI * 32 + p];
    const float* src1 = tok + ((size_t)bI * 512 + pos) * Hq;
    const float* src2 = pool + (size_t)bI * Hq;
    for (int g = lane; g < 384; g += 64) {
      const float* s = (g < 192) ? (src1 + g * 4) : (src2 + (g - 192) * 4);
      *(float4*)&hrow[w][g * 4] = *(const float4*)s;
    }
  }
  __syncthreads();

  // dot: wave w covers k in [w*384, w*384+384); lane: c = lane&31, kh = lane>>5
  const int c  = lane & 31;
  const int kh = lane >> 5;
  float a0 = 0.f, a1 = 0.f, a2 = 0.f, a3 = 0.f;
  if (c < Lq) {
    const int k0 = w * 384 + kh * 192;
    const float* wp = W123 + (size_t)k0 * Lq + c;    // 30 lanes = 120 B coalesced
    const float* h0 = &hrow[0][k0];
    const float* h1 = &hrow[1][k0];
    const float* h2 = &hrow[2][k0];
    const float* h3 = &hrow[3][k0];
    #pragma unroll 4
    for (int i = 0; i < 192; ++i) {
      const float wv = wp[(size_t)i * Lq];
      a0 = fmaf(h0[i], wv, a0);
      a1 = fmaf(h1[i], wv, a1);
      a2 = fmaf(h2[i], wv, a2);
      a3 = fmaf(h3[i], wv, a3);
    }
  }
  a0 += __shfl_xor(a0, 32);
  a1 += __shfl_xor(a1, 32);
  a2 += __shfl_xor(a2, 32);
  a3 += __shfl_xor(a3, 32);
  if (lane < Lq) {
    red2[w][0][lane] = a0; red2[w][1][lane] = a1;
    red2[w][2][lane] = a2; red2[w][3][lane] = a3;
  }
  __syncthreads();

  // wave w finalizes row w (ballot semantics: only lanes 0..29 active, as before)
  const int m = mbase + w;
  const bool act = lane < Lq;
  float logit = 0.f, lab = 0.f;
  if (act) {
    logit = red2[0][w][lane] + red2[1][w][lane] + red2[2][w][lane]
          + red2[3][w][lane] + btot[lane];
    lab = labels[(size_t)m * Lq + lane];
  }

  const unsigned long long validmask = __ballot(act && lab != -1.0f);
  const unsigned long long outmask   = __ballot(act && logit > 0.0f);
  const unsigned long long labmask   = __ballot(act && lab == 1.0f);
  const bool valid = (validmask != 0ULL);
  const int count_out = __popcll(outmask);
  const int count_lab = __popcll(labmask);

  float bce = 0.f;
  if (act && valid) {
    const float x = logit;
    bce = fmaxf(x, 0.f) + log1pf(expf(-fabsf(x))) - x * lab;
  }
  bce += __shfl_xor(bce, 16); bce += __shfl_xor(bce, 8);
  bce += __shfl_xor(bce, 4);  bce += __shfl_xor(bce, 2);
  bce += __shfl_xor(bce, 1);

  if (lane == 0) {
    float pb = 0.f, pv = 0.f, pc = 0.f, pe = 0.f, pp = 0.f;
    if (valid) {
      pb = bce; pv = 1.f;
      const float d = (float)count_out - (float)count_lab;
      pc = d * d;
    }
    if (count_out == 1 && count_lab == 1) {
      const float po = (float)(__ffsll((long long)outmask) - 1);
      const float pl = (float)(__ffsll((long long)labmask) - 1);
      pe = 1.f;
      const float dp = po - pl;
      pp = dp * dp;
    }
    red[w][0] = pb; red[w][1] = pv; red[w][2] = pc; red[w][3] = pe; red[w][4] = pp;
  }
  __syncthreads();
  if (tid < 5) {
    part[blockIdx.x * 5 + tid] =
        red[0][tid] + red[1][tid] + red[2][tid] + red[3][tid];
  }
}

// ---------- finalize: sum NBLK 5-float partials -> scalar loss
__global__ __launch_bounds__(256)
void finalize_kernel(const float* __restrict__ part, float* __restrict__ out) {
  __shared__ float red[32][5];
  const int t = threadIdx.x;
  if (t < 160) {
    const int j = t % 5, grp = t / 5;
    float s = 0.f;
    for (int i = grp; i < NBLK; i += 32) s += part[i * 5 + j];
    red[grp][j] = s;
  }
  __syncthreads();
  if (t == 0) {
    float t0 = 0.f, t1 = 0.f, t2 = 0.f, t3 = 0.f, t4 = 0.f;
    #pragma unroll
    for (int g = 0; g < 32; ++g) {
      t0 += red[g][0]; t1 += red[g][1]; t2 += red[g][2];
      t3 += red[g][3]; t4 += red[g][4];
    }
    const float bce = t0 / (t1 * (float)Lq);
    const float cnt = 10.0f * t2 / (float)Mq;
    const float pos = (t3 > 0.f) ? 5.0f * t4 / fmaxf(t3, 1.0f) : 0.f;
    out[0] = bce + cnt + pos;
  }
}

extern "C" void kernel_launch(void* const* d_in, const int* in_sizes, int n_in,
                              void* d_out, int out_size, void* d_ws, size_t ws_size,
                              hipStream_t stream) {
  const float* tok    = (const float*)d_in[0];
  const float* pool   = (const float*)d_in[1];
  const int*   npos   = (const int*)  d_in[2];
  const float* labels = (const float*)d_in[3];
  const float* W1     = (const float*)d_in[4];
  const float* b1     = (const float*)d_in[5];
  const float* W2     = (const float*)d_in[6];
  const float* b2     = (const float*)d_in[7];
  const float* W3     = (const float*)d_in[8];
  const float* b3     = (const float*)d_in[9];
  float* out = (float*)d_out;

  char* ws = (char*)d_ws;
  float* W23p   = (float*)(ws + 0x00000000);  // 240 KB [2][1024][30] k-major partials
  float* W123   = (float*)(ws + 0x00040000);  // 180 KB [1536][30] k-major
  float* beff23 = (float*)(ws + 0x00070000);  // 120 B
  float* btot   = (float*)(ws + 0x00070200);  // 120 B
  float* part   = (float*)(ws + 0x00071000);  // 10 KB [512][5]

  prep1<<<289, 256, 0, stream>>>(W2, W3, b2, b3, W1, W23p, beff23);
  prep2<<<181, 256, 0, stream>>>(W1, b1, W23p, beff23, W123, btot);
  loss_kernel<<<NBLK, 256, 0, stream>>>(tok, pool, npos, W123, btot, labels, part);
  finalize_kernel<<<1, 256, 0, stream>>>(part, out);
}